// Round 1
// baseline (2498.297 us; speedup 1.0000x reference)
//
#include <hip/hip_runtime.h>
#include <cstdint>
#include <cstddef>

typedef unsigned short u16;
typedef __attribute__((ext_vector_type(8))) short bf16x8;
typedef __attribute__((ext_vector_type(4))) float f32x4;

#define N_TOK 16384
#define DIM   1024
#define HID   4096
#define NEXP  8
#define HR    2048

__device__ __forceinline__ u16 f2bf(float f) {
  union { float f; uint32_t u; } x; x.f = f;
  uint32_t r = x.u + 0x7FFFu + ((x.u >> 16) & 1u);
  return (u16)(r >> 16);
}
__device__ __forceinline__ float bf2f(u16 u) {
  union { uint32_t u; float f; } x; x.u = ((uint32_t)u) << 16; return x.f;
}

__device__ __forceinline__ void async16(const void* g, const void* l) {
  auto gp = reinterpret_cast<const __attribute__((address_space(1))) uint32_t*>(
      reinterpret_cast<uintptr_t>(g));
  auto lp = reinterpret_cast<__attribute__((address_space(3))) uint32_t*>(
      reinterpret_cast<uintptr_t>(l));
  __builtin_amdgcn_global_load_lds(gp, lp, 16, 0, 0);
}

// ---------------- transpose + fp32->bf16 convert (optionally hi/lo split) ----
// src [R,C] fp32 (batched, blockIdx.z), dst [C,R] bf16 (+ lo residual)
template<bool SPLIT>
__global__ __launch_bounds__(256)
void transpose_cvt(const float* __restrict__ src, u16* __restrict__ hi,
                   u16* __restrict__ lo, int R, int C)
{
  __shared__ float tile[32][33];
  const size_t bofs = (size_t)blockIdx.z * R * C;
  src += bofs; hi += bofs; if (SPLIT) lo += bofs;
  const int tx = threadIdx.x, ty = threadIdx.y;  // (32, 8)
  const int c0 = blockIdx.x * 32, r0 = blockIdx.y * 32;
#pragma unroll
  for (int i = 0; i < 4; ++i)
    tile[ty + i * 8][tx] = src[(size_t)(r0 + ty + i * 8) * C + c0 + tx];
  __syncthreads();
#pragma unroll
  for (int i = 0; i < 4; ++i) {
    float v = tile[tx][ty + i * 8];
    size_t o = (size_t)(c0 + ty + i * 8) * R + r0 + tx;
    u16 h = f2bf(v);
    hi[o] = h;
    if (SPLIT) lo[o] = f2bf(v - bf2f(h));
  }
}

// ---------------- LayerNorm -> xn_hi/xn_lo bf16, out = x (residual init) ----
__global__ __launch_bounds__(256)
void ln_kernel(const float* __restrict__ x, const float* __restrict__ g,
               const float* __restrict__ b, u16* __restrict__ xh,
               u16* __restrict__ xl, float* __restrict__ out)
{
  const int row = blockIdx.x;
  const int t = threadIdx.x;
  const float4 xv = ((const float4*)(x + (size_t)row * DIM))[t];
  float s = xv.x + xv.y + xv.z + xv.w;
  float q = xv.x * xv.x + xv.y * xv.y + xv.z * xv.z + xv.w * xv.w;
#pragma unroll
  for (int off = 32; off; off >>= 1) {
    s += __shfl_down(s, off, 64);
    q += __shfl_down(q, off, 64);
  }
  __shared__ float sm[8];
  __shared__ float mu_s, rs_s;
  const int lane = t & 63, wv = t >> 6;
  if (lane == 0) { sm[wv] = s; sm[wv + 4] = q; }
  __syncthreads();
  if (t == 0) {
    float S = sm[0] + sm[1] + sm[2] + sm[3];
    float Q = sm[4] + sm[5] + sm[6] + sm[7];
    float mu = S * (1.f / DIM);
    float var = Q * (1.f / DIM) - mu * mu;
    mu_s = mu; rs_s = rsqrtf(var + 1e-5f);
  }
  __syncthreads();
  const float mu = mu_s, rs = rs_s;
  const float4 gv = ((const float4*)g)[t];
  const float4 bv = ((const float4*)b)[t];
  float n0 = (xv.x - mu) * rs * gv.x + bv.x;
  float n1 = (xv.y - mu) * rs * gv.y + bv.y;
  float n2 = (xv.z - mu) * rs * gv.z + bv.z;
  float n3 = (xv.w - mu) * rs * gv.w + bv.w;
  ushort4 h, l;
  h.x = f2bf(n0); l.x = f2bf(n0 - bf2f(h.x));
  h.y = f2bf(n1); l.y = f2bf(n1 - bf2f(h.y));
  h.z = f2bf(n2); l.z = f2bf(n2 - bf2f(h.z));
  h.w = f2bf(n3); l.w = f2bf(n3 - bf2f(h.w));
  ((ushort4*)(xh + (size_t)row * DIM))[t] = h;
  ((ushort4*)(xl + (size_t)row * DIM))[t] = l;
  ((float4*)(out + (size_t)row * DIM))[t] = xv;
}

// ---------------- router finish: logits (fp32), top-2, gates, scatter -------
__global__ __launch_bounds__(256)
void router_finish(const float* __restrict__ Hr, const float* __restrict__ w2,
                   const float* __restrict__ b2, int* __restrict__ rowsL,
                   float* __restrict__ gateL, int* __restrict__ cnts)
{
  const int lane = threadIdx.x & 63, wv = threadIdx.x >> 6;
  const int row = blockIdx.x * 4 + wv;
  const float* hr = Hr + (size_t)row * HR;
  float p[8] = {0, 0, 0, 0, 0, 0, 0, 0};
#pragma unroll 4
  for (int j = 0; j < HR / 64; ++j) {
    int col = j * 64 + lane;
    float v = hr[col];
    const float4* wp = (const float4*)(w2 + (size_t)col * 8);
    float4 w0 = wp[0], w1 = wp[1];
    p[0] += v * w0.x; p[1] += v * w0.y; p[2] += v * w0.z; p[3] += v * w0.w;
    p[4] += v * w1.x; p[5] += v * w1.y; p[6] += v * w1.z; p[7] += v * w1.w;
  }
#pragma unroll
  for (int off = 32; off; off >>= 1) {
#pragma unroll
    for (int e = 0; e < 8; ++e) p[e] += __shfl_down(p[e], off, 64);
  }
  if (lane == 0) {
    float l[8];
#pragma unroll
    for (int e = 0; e < 8; ++e) l[e] = p[e] + b2[e];
    int i0 = 0; float l0 = l[0];
#pragma unroll
    for (int e = 1; e < 8; ++e) if (l[e] > l0) { l0 = l[e]; i0 = e; }
    int i1 = -1; float l1 = -1e30f;
#pragma unroll
    for (int e = 0; e < 8; ++e) if (e != i0 && l[e] > l1) { l1 = l[e]; i1 = e; }
    float tt = expf(l1 - l0);            // <= 1
    float g0 = 1.f / (1.f + tt);
    float g1 = tt / (1.f + tt);
    int s0 = atomicAdd(&cnts[i0], 1);
    rowsL[(size_t)i0 * N_TOK + s0] = row; gateL[(size_t)i0 * N_TOK + s0] = g0;
    int s1 = atomicAdd(&cnts[i1], 1);
    rowsL[(size_t)i1 * N_TOK + s1] = row; gateL[(size_t)i1 * N_TOK + s1] = g1;
  }
}

// ---------------- GEMM: C[M,N] = A[M,K] * Bt[N,K]^T (bf16 MFMA) -------------
// SPLIT: 3-term hi/lo compensated product.
// EPI 0: Cf32[m,n] = relu(acc+bias)   (fp32)
// EPI 1: Cbf[m,n]  = bf16(relu(acc+bias))
// EPI 2: atomicAdd(Cf32[rows[m], n], gates[m]*(acc+bias))
// GATHER: A row index via rows[] list.
template<bool SPLIT, int EPI, bool GATHER>
__global__ __launch_bounds__(256, 2)
void gemm_bt(const u16* __restrict__ A0, const u16* __restrict__ A1,
             const u16* __restrict__ B0, const u16* __restrict__ B1,
             int lda, int ldb, int K, int M,
             const int* __restrict__ counts, int expert,
             const int* __restrict__ rowsAll, const float* __restrict__ gatesAll,
             const float* __restrict__ bias,
             u16* __restrict__ Cbf, float* __restrict__ Cf32, int ldc)
{
  const int Mq = counts ? counts[expert] : M;
  const int m0 = blockIdx.y * 128;
  if (m0 >= Mq) return;
  const int n0 = blockIdx.x * 128;
  const int* rows = rowsAll ? rowsAll + (size_t)expert * N_TOK : nullptr;
  const float* gates = gatesAll ? gatesAll + (size_t)expert * N_TOK : nullptr;

  __shared__ u16 As0[128 * 32], Bs0[128 * 32];
  __shared__ u16 As1[SPLIT ? 128 * 32 : 8], Bs1[SPLIT ? 128 * 32 : 8];

  const int t = threadIdx.x;
  size_t aoff[2]; int acodd[2]; size_t boff[2];
#pragma unroll
  for (int i = 0; i < 2; ++i) {
    int gdx = i * 256 + t;
    int ar = gdx >> 2, ac = (gdx & 3) * 8;
    int am = m0 + ar;
    int amc = am < Mq ? am : (Mq - 1);
    int agr;
    if (GATHER) agr = rows[amc];
    else        agr = amc;
    aoff[i] = (size_t)agr * lda + ac;
    boff[i] = (size_t)(n0 + ar) * ldb + ac;
    acodd[i] = gdx * 8;
  }

  f32x4 acc[4][4];
#pragma unroll
  for (int i = 0; i < 4; ++i)
#pragma unroll
    for (int j = 0; j < 4; ++j) acc[i][j] = (f32x4){0.f, 0.f, 0.f, 0.f};

  const int lane = t & 63, wv = t >> 6;
  const int wm = (wv >> 1) * 64, wn = (wv & 1) * 64;
  const int fr = lane & 15, fq = lane >> 4;

  for (int k0 = 0; k0 < K; k0 += 32) {
    __syncthreads();
#pragma unroll
    for (int i = 0; i < 2; ++i) {
      async16(A0 + aoff[i] + k0, &As0[acodd[i]]);
      async16(B0 + boff[i] + k0, &Bs0[acodd[i]]);
      if (SPLIT) {
        async16(A1 + aoff[i] + k0, &As1[acodd[i]]);
        async16(B1 + boff[i] + k0, &Bs1[acodd[i]]);
      }
    }
    __syncthreads();
    bf16x8 af[4], bfr[4], af1[4], bf1[4];
#pragma unroll
    for (int xi = 0; xi < 4; ++xi) {
      af[xi]  = *(const bf16x8*)&As0[(wm + xi * 16 + fr) * 32 + fq * 8];
      bfr[xi] = *(const bf16x8*)&Bs0[(wn + xi * 16 + fr) * 32 + fq * 8];
      if (SPLIT) {
        af1[xi] = *(const bf16x8*)&As1[(wm + xi * 16 + fr) * 32 + fq * 8];
        bf1[xi] = *(const bf16x8*)&Bs1[(wn + xi * 16 + fr) * 32 + fq * 8];
      }
    }
#pragma unroll
    for (int mt = 0; mt < 4; ++mt)
#pragma unroll
      for (int nt = 0; nt < 4; ++nt) {
        acc[mt][nt] = __builtin_amdgcn_mfma_f32_16x16x32_bf16(af[mt], bfr[nt], acc[mt][nt], 0, 0, 0);
        if (SPLIT) {
          acc[mt][nt] = __builtin_amdgcn_mfma_f32_16x16x32_bf16(af[mt], bf1[nt], acc[mt][nt], 0, 0, 0);
          acc[mt][nt] = __builtin_amdgcn_mfma_f32_16x16x32_bf16(af1[mt], bfr[nt], acc[mt][nt], 0, 0, 0);
        }
      }
  }

  // epilogue: C/D layout col = lane&15, row = (lane>>4)*4 + reg
#pragma unroll
  for (int mt = 0; mt < 4; ++mt) {
#pragma unroll
    for (int nt = 0; nt < 4; ++nt) {
      const int n = n0 + wn + nt * 16 + fr;
      const float bv = bias[n];
#pragma unroll
      for (int r = 0; r < 4; ++r) {
        const int m = m0 + wm + mt * 16 + fq * 4 + r;
        if (m < Mq) {
          float v = acc[mt][nt][r] + bv;
          if constexpr (EPI == 0) {
            Cf32[(size_t)m * ldc + n] = fmaxf(v, 0.f);
          } else if constexpr (EPI == 1) {
            Cbf[(size_t)m * ldc + n] = f2bf(fmaxf(v, 0.f));
          } else {
            atomicAdd(&Cf32[(size_t)rows[m] * ldc + n], gates[m] * v);
          }
        }
      }
    }
  }
}

extern "C" void kernel_launch(void* const* d_in, const int* in_sizes, int n_in,
                              void* d_out, int out_size, void* d_ws, size_t ws_size,
                              hipStream_t stream)
{
  const float* x    = (const float*)d_in[0];
  const float* ln_g = (const float*)d_in[1];
  const float* ln_b = (const float*)d_in[2];
  const float* r_w1 = (const float*)d_in[3];
  const float* r_b1 = (const float*)d_in[4];
  const float* r_w2 = (const float*)d_in[5];
  const float* r_b2 = (const float*)d_in[6];
  const float* e_w1 = (const float*)d_in[7];
  const float* e_b1 = (const float*)d_in[8];
  const float* e_w2 = (const float*)d_in[9];
  const float* e_b2 = (const float*)d_in[10];
  float* out = (float*)d_out;

  char* ws = (char*)d_ws;
  const size_t MB = 1024ull * 1024ull;
  u16*   xnhi = (u16*)(ws);                 // 32 MB  [N, D] bf16
  u16*   xnlo = (u16*)(ws + 32 * MB);       // 32 MB
  u16*   rw1h = (u16*)(ws + 64 * MB);       // 4 MB   [HR, D] bf16
  u16*   rw1l = (u16*)(ws + 68 * MB);       // 4 MB
  u16*   ew1t = (u16*)(ws + 72 * MB);       // 64 MB  [E][H, D] bf16
  u16*   ew2t = (u16*)(ws + 136 * MB);      // 64 MB  [E][D, H] bf16
  float* Hr   = (float*)(ws + 200 * MB);    // 128 MB [N, HR] fp32 (reused:)
  u16*   Hbuf = (u16*)(ws + 200 * MB);      //        [N, H] bf16 per-expert
  int*   rowsL = (int*)(ws + 328 * MB);     // 512 KB [E][N]
  float* gateL = (float*)(ws + 328 * MB + 512 * 1024);  // 512 KB
  int*   cnts  = (int*)(ws + 329 * MB);     // 64 B
  (void)ws_size; (void)in_sizes; (void)n_in; (void)out_size;

  hipMemsetAsync(cnts, 0, 64, stream);

  dim3 tb(32, 8);
  transpose_cvt<true ><<<dim3(HR / 32, DIM / 32, 1), tb, 0, stream>>>(r_w1, rw1h, rw1l, DIM, HR);
  transpose_cvt<false><<<dim3(HID / 32, DIM / 32, NEXP), tb, 0, stream>>>(e_w1, ew1t, nullptr, DIM, HID);
  transpose_cvt<false><<<dim3(DIM / 32, HID / 32, NEXP), tb, 0, stream>>>(e_w2, ew2t, nullptr, HID, DIM);

  ln_kernel<<<N_TOK, 256, 0, stream>>>(x, ln_g, ln_b, xnhi, xnlo, out);

  // router GEMM1 (split 3-term): Hr = relu(xn @ r_w1 + r_b1)  [N, HR] fp32
  gemm_bt<true, 0, false><<<dim3(HR / 128, N_TOK / 128), 256, 0, stream>>>(
      xnhi, xnlo, rw1h, rw1l, DIM, DIM, DIM, N_TOK,
      nullptr, 0, nullptr, nullptr, r_b1, nullptr, Hr, HR);

  router_finish<<<N_TOK / 4, 256, 0, stream>>>(Hr, r_w2, r_b2, rowsL, gateL, cnts);

  for (int e = 0; e < NEXP; ++e) {
    // H = relu(xn[rows] @ e_w1[e] + e_b1[e])  [Me, H] bf16
    gemm_bt<false, 1, true><<<dim3(HID / 128, N_TOK / 128), 256, 0, stream>>>(
        xnhi, nullptr, ew1t + (size_t)e * HID * DIM, nullptr,
        DIM, DIM, DIM, N_TOK,
        cnts, e, rowsL, nullptr, e_b1 + (size_t)e * HID, Hbuf, nullptr, HID);
    // out[rows] += gate * (H @ e_w2[e] + e_b2[e])
    gemm_bt<false, 2, false><<<dim3(DIM / 128, N_TOK / 128), 256, 0, stream>>>(
        Hbuf, nullptr, ew2t + (size_t)e * DIM * HID, nullptr,
        HID, HID, HID, N_TOK,
        cnts, e, rowsL, gateL, e_b2 + (size_t)e * DIM, nullptr, out, DIM);
  }
}

// Round 2
// 2217.713 us; speedup vs baseline: 1.1265x; 1.1265x over previous
//
#include <hip/hip_runtime.h>
#include <cstdint>
#include <cstddef>

typedef unsigned short u16;
typedef __attribute__((ext_vector_type(8))) short bf16x8;
typedef __attribute__((ext_vector_type(4))) float f32x4;

#define N_TOK 16384
#define DIM   1024
#define HID   4096
#define NEXP  8
#define HR    2048

__device__ __forceinline__ u16 f2bf(float f) {
  union { float f; uint32_t u; } x; x.f = f;
  uint32_t r = x.u + 0x7FFFu + ((x.u >> 16) & 1u);
  return (u16)(r >> 16);
}
__device__ __forceinline__ float bf2f(u16 u) {
  union { uint32_t u; float f; } x; x.u = ((uint32_t)u) << 16; return x.f;
}

__device__ __forceinline__ void async16(const void* g, const void* l) {
  auto gp = reinterpret_cast<const __attribute__((address_space(1))) uint32_t*>(
      reinterpret_cast<uintptr_t>(g));
  auto lp = reinterpret_cast<__attribute__((address_space(3))) uint32_t*>(
      reinterpret_cast<uintptr_t>(l));
  __builtin_amdgcn_global_load_lds(gp, lp, 16, 0, 0);
}

// ---------------- transpose + fp32->bf16 convert (optionally hi/lo split) ----
template<bool SPLIT>
__global__ __launch_bounds__(256)
void transpose_cvt(const float* __restrict__ src, u16* __restrict__ hi,
                   u16* __restrict__ lo, int R, int C)
{
  __shared__ float tile[32][33];
  const size_t bofs = (size_t)blockIdx.z * R * C;
  src += bofs; hi += bofs; if (SPLIT) lo += bofs;
  const int tx = threadIdx.x, ty = threadIdx.y;  // (32, 8)
  const int c0 = blockIdx.x * 32, r0 = blockIdx.y * 32;
#pragma unroll
  for (int i = 0; i < 4; ++i)
    tile[ty + i * 8][tx] = src[(size_t)(r0 + ty + i * 8) * C + c0 + tx];
  __syncthreads();
#pragma unroll
  for (int i = 0; i < 4; ++i) {
    float v = tile[tx][ty + i * 8];
    size_t o = (size_t)(c0 + ty + i * 8) * R + r0 + tx;
    u16 h = f2bf(v);
    hi[o] = h;
    if (SPLIT) lo[o] = f2bf(v - bf2f(h));
  }
}

// ---------------- LayerNorm -> xn_hi/xn_lo bf16, out = x (residual init) ----
__global__ __launch_bounds__(256)
void ln_kernel(const float* __restrict__ x, const float* __restrict__ g,
               const float* __restrict__ b, u16* __restrict__ xh,
               u16* __restrict__ xl, float* __restrict__ out)
{
  const int row = blockIdx.x;
  const int t = threadIdx.x;
  const float4 xv = ((const float4*)(x + (size_t)row * DIM))[t];
  float s = xv.x + xv.y + xv.z + xv.w;
  float q = xv.x * xv.x + xv.y * xv.y + xv.z * xv.z + xv.w * xv.w;
#pragma unroll
  for (int off = 32; off; off >>= 1) {
    s += __shfl_down(s, off, 64);
    q += __shfl_down(q, off, 64);
  }
  __shared__ float sm[8];
  __shared__ float mu_s, rs_s;
  const int lane = t & 63, wv = t >> 6;
  if (lane == 0) { sm[wv] = s; sm[wv + 4] = q; }
  __syncthreads();
  if (t == 0) {
    float S = sm[0] + sm[1] + sm[2] + sm[3];
    float Q = sm[4] + sm[5] + sm[6] + sm[7];
    float mu = S * (1.f / DIM);
    float var = Q * (1.f / DIM) - mu * mu;
    mu_s = mu; rs_s = rsqrtf(var + 1e-5f);
  }
  __syncthreads();
  const float mu = mu_s, rs = rs_s;
  const float4 gv = ((const float4*)g)[t];
  const float4 bv = ((const float4*)b)[t];
  float n0 = (xv.x - mu) * rs * gv.x + bv.x;
  float n1 = (xv.y - mu) * rs * gv.y + bv.y;
  float n2 = (xv.z - mu) * rs * gv.z + bv.z;
  float n3 = (xv.w - mu) * rs * gv.w + bv.w;
  ushort4 h, l;
  h.x = f2bf(n0); l.x = f2bf(n0 - bf2f(h.x));
  h.y = f2bf(n1); l.y = f2bf(n1 - bf2f(h.y));
  h.z = f2bf(n2); l.z = f2bf(n2 - bf2f(h.z));
  h.w = f2bf(n3); l.w = f2bf(n3 - bf2f(h.w));
  ((ushort4*)(xh + (size_t)row * DIM))[t] = h;
  ((ushort4*)(xl + (size_t)row * DIM))[t] = l;
  ((float4*)(out + (size_t)row * DIM))[t] = xv;
}

// ---------------- top-2 + gates + compacted scatter (few atomics) -----------
__global__ __launch_bounds__(256)
void topk_kernel(const float* __restrict__ logits, const float* __restrict__ b2,
                 int* __restrict__ rowsL, float* __restrict__ gateL,
                 int* __restrict__ cnts)
{
  __shared__ int lcnt[NEXP];
  __shared__ int sbase[NEXP];
  const int t = threadIdx.x;
  const int row = blockIdx.x * 256 + t;
  if (t < NEXP) lcnt[t] = 0;
  float l[8];
  const float4* lp = (const float4*)(logits + (size_t)row * 8);
  float4 l04 = lp[0], l14 = lp[1];
  l[0] = l04.x + b2[0]; l[1] = l04.y + b2[1]; l[2] = l04.z + b2[2]; l[3] = l04.w + b2[3];
  l[4] = l14.x + b2[4]; l[5] = l14.y + b2[5]; l[6] = l14.z + b2[6]; l[7] = l14.w + b2[7];
  int i0 = 0; float l0 = l[0];
#pragma unroll
  for (int e = 1; e < 8; ++e) if (l[e] > l0) { l0 = l[e]; i0 = e; }
  int i1 = -1; float l1 = -1e30f;
#pragma unroll
  for (int e = 0; e < 8; ++e) if (e != i0 && l[e] > l1) { l1 = l[e]; i1 = e; }
  float tt = expf(l1 - l0);            // <= 1
  float g0 = 1.f / (1.f + tt);
  float g1 = tt / (1.f + tt);
  __syncthreads();
  int r0 = atomicAdd(&lcnt[i0], 1);
  int r1 = atomicAdd(&lcnt[i1], 1);
  __syncthreads();
  if (t < NEXP) sbase[t] = atomicAdd(&cnts[t], lcnt[t]);
  __syncthreads();
  int s0 = sbase[i0] + r0;
  int s1 = sbase[i1] + r1;
  rowsL[(size_t)i0 * N_TOK + s0] = row; gateL[(size_t)i0 * N_TOK + s0] = g0;
  rowsL[(size_t)i1 * N_TOK + s1] = row; gateL[(size_t)i1 * N_TOK + s1] = g1;
}

// ---------------- GEMM: C[M,N] = A[M,K] * Bt[N,K]^T (bf16 MFMA) -------------
// SPLIT: 3-term hi/lo compensated product.
// EPI 1: Cbf[m,n]  = bf16(relu(acc+bias))
// EPI 2: atomicAdd(Cf32[rows[m], n], gates[m]*(acc+bias_if_z0))  [split-K via z]
// EPI 3: logits fusion: v=relu(acc+bias); atomicAdd(logits[m][e], sum_n v*w2[n][e])
// GATHER: A row index via rows[] list. K = per-z K length; z-offset = z*K.
template<bool SPLIT, int EPI, bool GATHER>
__global__ __launch_bounds__(256, 2)
void gemm_bt(const u16* __restrict__ A0, const u16* __restrict__ A1,
             const u16* __restrict__ B0, const u16* __restrict__ B1,
             int lda, int ldb, int K, int M,
             const int* __restrict__ counts, int expert,
             const int* __restrict__ rowsAll, const float* __restrict__ gatesAll,
             const float* __restrict__ bias,
             const float* __restrict__ w2, float* __restrict__ logits,
             u16* __restrict__ Cbf, float* __restrict__ Cf32, int ldc)
{
  const int Mq = counts ? counts[expert] : M;
  const int m0 = blockIdx.y * 128;
  if (m0 >= Mq) return;
  const int n0 = blockIdx.x * 128;
  const int zOff = blockIdx.z * K;
  const int* rows = rowsAll ? rowsAll + (size_t)expert * N_TOK : nullptr;
  const float* gates = gatesAll ? gatesAll + (size_t)expert * N_TOK : nullptr;

  __shared__ u16 As0[128 * 32], Bs0[128 * 32];
  __shared__ u16 As1[SPLIT ? 128 * 32 : 8], Bs1[SPLIT ? 128 * 32 : 8];

  const int t = threadIdx.x;
  size_t aoff[2]; int acodd[2]; size_t boff[2];
#pragma unroll
  for (int i = 0; i < 2; ++i) {
    int gdx = i * 256 + t;
    int ar = gdx >> 2, ac = (gdx & 3) * 8;
    int am = m0 + ar;
    int amc = am < Mq ? am : (Mq - 1);
    int agr;
    if (GATHER) agr = rows[amc];
    else        agr = amc;
    aoff[i] = (size_t)agr * lda + ac + zOff;
    boff[i] = (size_t)(n0 + ar) * ldb + ac + zOff;
    acodd[i] = gdx * 8;
  }

  f32x4 acc[4][4];
#pragma unroll
  for (int i = 0; i < 4; ++i)
#pragma unroll
    for (int j = 0; j < 4; ++j) acc[i][j] = (f32x4){0.f, 0.f, 0.f, 0.f};

  const int lane = t & 63, wv = t >> 6;
  const int wm = (wv >> 1) * 64, wn = (wv & 1) * 64;
  const int fr = lane & 15, fq = lane >> 4;

  for (int k0 = 0; k0 < K; k0 += 32) {
    __syncthreads();
#pragma unroll
    for (int i = 0; i < 2; ++i) {
      async16(A0 + aoff[i] + k0, &As0[acodd[i]]);
      async16(B0 + boff[i] + k0, &Bs0[acodd[i]]);
      if (SPLIT) {
        async16(A1 + aoff[i] + k0, &As1[acodd[i]]);
        async16(B1 + boff[i] + k0, &Bs1[acodd[i]]);
      }
    }
    __syncthreads();
    bf16x8 af[4], bfr[4], af1[4], bf1[4];
#pragma unroll
    for (int xi = 0; xi < 4; ++xi) {
      af[xi]  = *(const bf16x8*)&As0[(wm + xi * 16 + fr) * 32 + fq * 8];
      bfr[xi] = *(const bf16x8*)&Bs0[(wn + xi * 16 + fr) * 32 + fq * 8];
      if (SPLIT) {
        af1[xi] = *(const bf16x8*)&As1[(wm + xi * 16 + fr) * 32 + fq * 8];
        bf1[xi] = *(const bf16x8*)&Bs1[(wn + xi * 16 + fr) * 32 + fq * 8];
      }
    }
#pragma unroll
    for (int mt = 0; mt < 4; ++mt)
#pragma unroll
      for (int nt = 0; nt < 4; ++nt) {
        acc[mt][nt] = __builtin_amdgcn_mfma_f32_16x16x32_bf16(af[mt], bfr[nt], acc[mt][nt], 0, 0, 0);
        if (SPLIT) {
          acc[mt][nt] = __builtin_amdgcn_mfma_f32_16x16x32_bf16(af[mt], bf1[nt], acc[mt][nt], 0, 0, 0);
          acc[mt][nt] = __builtin_amdgcn_mfma_f32_16x16x32_bf16(af1[mt], bfr[nt], acc[mt][nt], 0, 0, 0);
        }
      }
  }

  // C/D layout: col = lane&15 (fr), row = fq*4 + reg
  if constexpr (EPI == 3) {
    // fused router logits: per-wave partial over its 128 n-columns
    float w2v[4][8]; float b1v[4];
#pragma unroll
    for (int nt = 0; nt < 4; ++nt) {
      const int n = n0 + wn + nt * 16 + fr;
      b1v[nt] = bias[n];
      const float4* wp = (const float4*)(w2 + (size_t)n * 8);
      float4 wa = wp[0], wb = wp[1];
      w2v[nt][0] = wa.x; w2v[nt][1] = wa.y; w2v[nt][2] = wa.z; w2v[nt][3] = wa.w;
      w2v[nt][4] = wb.x; w2v[nt][5] = wb.y; w2v[nt][6] = wb.z; w2v[nt][7] = wb.w;
    }
#pragma unroll
    for (int mt = 0; mt < 4; ++mt) {
      float pe[4][8];
#pragma unroll
      for (int r = 0; r < 4; ++r)
#pragma unroll
        for (int e = 0; e < 8; ++e) pe[r][e] = 0.f;
#pragma unroll
      for (int nt = 0; nt < 4; ++nt)
#pragma unroll
        for (int r = 0; r < 4; ++r) {
          float v = fmaxf(acc[mt][nt][r] + b1v[nt], 0.f);
#pragma unroll
          for (int e = 0; e < 8; ++e) pe[r][e] += v * w2v[nt][e];
        }
      // reduce across the 16 fr-lanes (xor bits 0..3 of lane id)
#pragma unroll
      for (int off = 1; off < 16; off <<= 1)
#pragma unroll
        for (int r = 0; r < 4; ++r)
#pragma unroll
          for (int e = 0; e < 8; ++e)
            pe[r][e] += __shfl_xor(pe[r][e], off, 64);
      if (fr == 0) {
#pragma unroll
        for (int r = 0; r < 4; ++r) {
          const int m = m0 + wm + mt * 16 + fq * 4 + r;
#pragma unroll
          for (int e = 0; e < 8; ++e)
            atomicAdd(&logits[(size_t)m * 8 + e], pe[r][e]);
        }
      }
    }
    return;
  }

#pragma unroll
  for (int mt = 0; mt < 4; ++mt) {
#pragma unroll
    for (int nt = 0; nt < 4; ++nt) {
      const int n = n0 + wn + nt * 16 + fr;
      const float bv = (blockIdx.z == 0) ? bias[n] : 0.f;
#pragma unroll
      for (int r = 0; r < 4; ++r) {
        const int m = m0 + wm + mt * 16 + fq * 4 + r;
        if (m < Mq) {
          float v = acc[mt][nt][r] + bv;
          if constexpr (EPI == 1) {
            Cbf[(size_t)m * ldc + n] = f2bf(fmaxf(v, 0.f));
          } else {
            atomicAdd(&Cf32[(size_t)rows[m] * ldc + n], gates[m] * v);
          }
        }
      }
    }
  }
}

extern "C" void kernel_launch(void* const* d_in, const int* in_sizes, int n_in,
                              void* d_out, int out_size, void* d_ws, size_t ws_size,
                              hipStream_t stream)
{
  const float* x    = (const float*)d_in[0];
  const float* ln_g = (const float*)d_in[1];
  const float* ln_b = (const float*)d_in[2];
  const float* r_w1 = (const float*)d_in[3];
  const float* r_b1 = (const float*)d_in[4];
  const float* r_w2 = (const float*)d_in[5];
  const float* r_b2 = (const float*)d_in[6];
  const float* e_w1 = (const float*)d_in[7];
  const float* e_b1 = (const float*)d_in[8];
  const float* e_w2 = (const float*)d_in[9];
  const float* e_b2 = (const float*)d_in[10];
  float* out = (float*)d_out;

  char* ws = (char*)d_ws;
  const size_t MB = 1024ull * 1024ull;
  u16*   xnhi = (u16*)(ws);                 // 32 MB  [N, D] bf16
  u16*   xnlo = (u16*)(ws + 32 * MB);       // 32 MB
  u16*   rw1h = (u16*)(ws + 64 * MB);       // 4 MB   [HR, D] bf16
  u16*   rw1l = (u16*)(ws + 68 * MB);       // 4 MB
  u16*   ew1t = (u16*)(ws + 72 * MB);       // 64 MB  [E][H, D] bf16
  u16*   ew2t = (u16*)(ws + 136 * MB);      // 64 MB  [E][D, H] bf16
  u16*   Hbuf = (u16*)(ws + 200 * MB);      // 128 MB [N, H] bf16 per-expert
  int*   rowsL = (int*)(ws + 328 * MB);     // 512 KB [E][N]
  float* gateL = (float*)(ws + 328 * MB + 512 * 1024);  // 512 KB
  int*   cnts  = (int*)(ws + 329 * MB);     // 64 B
  float* logits = (float*)(ws + 329 * MB + 1024);  // 512 KB [N, 8]
  (void)ws_size; (void)in_sizes; (void)n_in; (void)out_size;

  hipMemsetAsync(cnts, 0, 64, stream);
  hipMemsetAsync(logits, 0, (size_t)N_TOK * 8 * sizeof(float), stream);

  dim3 tb(32, 8);
  transpose_cvt<true ><<<dim3(HR / 32, DIM / 32, 1), tb, 0, stream>>>(r_w1, rw1h, rw1l, DIM, HR);
  transpose_cvt<false><<<dim3(HID / 32, DIM / 32, NEXP), tb, 0, stream>>>(e_w1, ew1t, nullptr, DIM, HID);
  transpose_cvt<false><<<dim3(DIM / 32, HID / 32, NEXP), tb, 0, stream>>>(e_w2, ew2t, nullptr, HID, DIM);

  ln_kernel<<<N_TOK, 256, 0, stream>>>(x, ln_g, ln_b, xnhi, xnlo, out);

  // router GEMM1 (split 3-term) with fused relu + @w2 logits epilogue
  gemm_bt<true, 3, false><<<dim3(HR / 128, N_TOK / 128), 256, 0, stream>>>(
      xnhi, xnlo, rw1h, rw1l, DIM, DIM, DIM, N_TOK,
      nullptr, 0, nullptr, nullptr, r_b1, r_w2, logits, nullptr, nullptr, 0);

  topk_kernel<<<N_TOK / 256, 256, 0, stream>>>(logits, r_b2, rowsL, gateL, cnts);

  for (int e = 0; e < NEXP; ++e) {
    // H = relu(xn[rows] @ e_w1[e] + e_b1[e])  [Me, H] bf16
    gemm_bt<false, 1, true><<<dim3(HID / 128, N_TOK / 128), 256, 0, stream>>>(
        xnhi, nullptr, ew1t + (size_t)e * HID * DIM, nullptr,
        DIM, DIM, DIM, N_TOK,
        cnts, e, rowsL, nullptr, e_b1 + (size_t)e * HID, nullptr, nullptr,
        Hbuf, nullptr, HID);
    // out[rows] += gate * (H @ e_w2[e] + e_b2[e])   (split-K = 2)
    gemm_bt<false, 2, false><<<dim3(DIM / 128, N_TOK / 128, 2), 256, 0, stream>>>(
        Hbuf, nullptr, ew2t + (size_t)e * DIM * HID, nullptr,
        HID, HID, HID / 2, N_TOK,
        cnts, e, rowsL, gateL, e_b2 + (size_t)e * DIM, nullptr, nullptr,
        nullptr, out, DIM);
  }
}

// Round 3
// 1600.960 us; speedup vs baseline: 1.5605x; 1.3852x over previous
//
#include <hip/hip_runtime.h>
#include <cstdint>
#include <cstddef>

typedef unsigned short u16;
typedef __attribute__((ext_vector_type(8))) short bf16x8;
typedef __attribute__((ext_vector_type(4))) float f32x4;

#define N_TOK 16384
#define DIM   1024
#define HID   4096
#define NEXP  8
#define HR    2048
#define TAU   0.02f

__device__ __forceinline__ u16 f2bf(float f) {
  union { float f; uint32_t u; } x; x.f = f;
  uint32_t r = x.u + 0x7FFFu + ((x.u >> 16) & 1u);
  return (u16)(r >> 16);
}
__device__ __forceinline__ float bf2f(u16 u) {
  union { uint32_t u; float f; } x; x.u = ((uint32_t)u) << 16; return x.f;
}

__device__ __forceinline__ void async16(const void* g, const void* l) {
  auto gp = reinterpret_cast<const __attribute__((address_space(1))) uint32_t*>(
      reinterpret_cast<uintptr_t>(g));
  auto lp = reinterpret_cast<__attribute__((address_space(3))) uint32_t*>(
      reinterpret_cast<uintptr_t>(l));
  __builtin_amdgcn_global_load_lds(gp, lp, 16, 0, 0);
}

// ---------------- transpose + fp32->bf16 convert (optionally hi/lo split) ----
template<bool SPLIT>
__global__ __launch_bounds__(256)
void transpose_cvt(const float* __restrict__ src, u16* __restrict__ hi,
                   u16* __restrict__ lo, int R, int C)
{
  __shared__ float tile[32][33];
  const size_t bofs = (size_t)blockIdx.z * R * C;
  src += bofs; hi += bofs; if (SPLIT) lo += bofs;
  const int tx = threadIdx.x, ty = threadIdx.y;  // (32, 8)
  const int c0 = blockIdx.x * 32, r0 = blockIdx.y * 32;
#pragma unroll
  for (int i = 0; i < 4; ++i)
    tile[ty + i * 8][tx] = src[(size_t)(r0 + ty + i * 8) * C + c0 + tx];
  __syncthreads();
#pragma unroll
  for (int i = 0; i < 4; ++i) {
    float v = tile[tx][ty + i * 8];
    size_t o = (size_t)(c0 + ty + i * 8) * R + r0 + tx;
    u16 h = f2bf(v);
    hi[o] = h;
    if (SPLIT) lo[o] = f2bf(v - bf2f(h));
  }
}

// ---------------- LayerNorm -> xn_hi/xn_lo bf16, out = x (residual init) ----
__global__ __launch_bounds__(256)
void ln_kernel(const float* __restrict__ x, const float* __restrict__ g,
               const float* __restrict__ b, u16* __restrict__ xh,
               u16* __restrict__ xl, float* __restrict__ out)
{
  const int row = blockIdx.x;
  const int t = threadIdx.x;
  const float4 xv = ((const float4*)(x + (size_t)row * DIM))[t];
  float s = xv.x + xv.y + xv.z + xv.w;
  float q = xv.x * xv.x + xv.y * xv.y + xv.z * xv.z + xv.w * xv.w;
#pragma unroll
  for (int off = 32; off; off >>= 1) {
    s += __shfl_down(s, off, 64);
    q += __shfl_down(q, off, 64);
  }
  __shared__ float sm[8];
  __shared__ float mu_s, rs_s;
  const int lane = t & 63, wv = t >> 6;
  if (lane == 0) { sm[wv] = s; sm[wv + 4] = q; }
  __syncthreads();
  if (t == 0) {
    float S = sm[0] + sm[1] + sm[2] + sm[3];
    float Q = sm[4] + sm[5] + sm[6] + sm[7];
    float mu = S * (1.f / DIM);
    float var = Q * (1.f / DIM) - mu * mu;
    mu_s = mu; rs_s = rsqrtf(var + 1e-5f);
  }
  __syncthreads();
  const float mu = mu_s, rs = rs_s;
  const float4 gv = ((const float4*)g)[t];
  const float4 bv = ((const float4*)b)[t];
  float n0 = (xv.x - mu) * rs * gv.x + bv.x;
  float n1 = (xv.y - mu) * rs * gv.y + bv.y;
  float n2 = (xv.z - mu) * rs * gv.z + bv.z;
  float n3 = (xv.w - mu) * rs * gv.w + bv.w;
  ushort4 h, l;
  h.x = f2bf(n0); l.x = f2bf(n0 - bf2f(h.x));
  h.y = f2bf(n1); l.y = f2bf(n1 - bf2f(h.y));
  h.z = f2bf(n2); l.z = f2bf(n2 - bf2f(h.z));
  h.w = f2bf(n3); l.w = f2bf(n3 - bf2f(h.w));
  ((ushort4*)(xh + (size_t)row * DIM))[t] = h;
  ((ushort4*)(xl + (size_t)row * DIM))[t] = l;
  ((float4*)(out + (size_t)row * DIM))[t] = xv;
}

// ---------------- logits = Hr(bf16) @ w2 (fp32), one block per row ----------
__global__ __launch_bounds__(256)
void logits_kernel(const u16* __restrict__ HrB, const float* __restrict__ w2,
                   float* __restrict__ logits)
{
  const int row = blockIdx.x, t = threadIdx.x;
  const u16* h = HrB + (size_t)row * HR;
  const ushort4* hv = (const ushort4*)(h + t * 8);
  ushort4 h0 = hv[0], h1 = hv[1];
  u16 hh[8] = {h0.x, h0.y, h0.z, h0.w, h1.x, h1.y, h1.z, h1.w};
  float p[8] = {0, 0, 0, 0, 0, 0, 0, 0};
#pragma unroll
  for (int j = 0; j < 8; ++j) {
    const int col = t * 8 + j;
    const float v = bf2f(hh[j]);
    const float4* wp = (const float4*)(w2 + (size_t)col * 8);
    float4 a = wp[0], b = wp[1];
    p[0] += v * a.x; p[1] += v * a.y; p[2] += v * a.z; p[3] += v * a.w;
    p[4] += v * b.x; p[5] += v * b.y; p[6] += v * b.z; p[7] += v * b.w;
  }
#pragma unroll
  for (int off = 32; off; off >>= 1)
#pragma unroll
    for (int e = 0; e < 8; ++e) p[e] += __shfl_down(p[e], off, 64);
  __shared__ float sm[4][8];
  const int lane = t & 63, wv = t >> 6;
  if (lane == 0) {
#pragma unroll
    for (int e = 0; e < 8; ++e) sm[wv][e] = p[e];
  }
  __syncthreads();
  if (t < 8)
    logits[(size_t)row * 8 + t] = sm[0][t] + sm[1][t] + sm[2][t] + sm[3][t];
}

__device__ __forceinline__ void load_logits(const float* logits, const float* b2,
                                            int row, float l[8]) {
  const float4* lp = (const float4*)(logits + (size_t)row * 8);
  float4 a = lp[0], b = lp[1];
  l[0] = a.x + b2[0]; l[1] = a.y + b2[1]; l[2] = a.z + b2[2]; l[3] = a.w + b2[3];
  l[4] = b.x + b2[4]; l[5] = b.y + b2[5]; l[6] = b.z + b2[6]; l[7] = b.w + b2[7];
}
__device__ __forceinline__ void top2(const float l[8], int& i0, float& l0,
                                     int& i1, float& l1) {
  i0 = 0; l0 = l[0];
#pragma unroll
  for (int e = 1; e < 8; ++e) if (l[e] > l0) { l0 = l[e]; i0 = e; }
  i1 = -1; l1 = -1e30f;
#pragma unroll
  for (int e = 0; e < 8; ++e) if (e != i0 && l[e] > l1) { l1 = l[e]; i1 = e; }
}

// ---------------- pass1: flag ambiguous rows, zero their logits -------------
__global__ __launch_bounds__(256)
void pass_flag(float* __restrict__ logits, const float* __restrict__ b2,
               int* __restrict__ fixL, int* __restrict__ cntFix)
{
  __shared__ int lcnt;
  __shared__ int base;
  const int t = threadIdx.x;
  const int row = blockIdx.x * 256 + t;
  if (t == 0) lcnt = 0;
  float l[8]; load_logits(logits, b2, row, l);
  int i0, i1; float l0, l1;
  top2(l, i0, l0, i1, l1);
  float l2 = -1e30f;
#pragma unroll
  for (int e = 0; e < 8; ++e)
    if (e != i0 && e != i1 && l[e] > l2) l2 = l[e];
  const bool flag = (l1 - l2) < TAU;
  __syncthreads();
  int r = 0;
  if (flag) r = atomicAdd(&lcnt, 1);
  __syncthreads();
  if (t == 0) base = atomicAdd(cntFix, lcnt);
  __syncthreads();
  if (flag) {
    fixL[base + r] = row;
    float4 z = {0.f, 0.f, 0.f, 0.f};
    ((float4*)(logits + (size_t)row * 8))[0] = z;
    ((float4*)(logits + (size_t)row * 8))[1] = z;
  }
}

// ---------------- pass_count / scan / pass_scatter --------------------------
__global__ __launch_bounds__(256)
void pass_count(const float* __restrict__ logits, const float* __restrict__ b2,
                int* __restrict__ cnts)
{
  __shared__ int lcnt[NEXP];
  const int t = threadIdx.x;
  const int row = blockIdx.x * 256 + t;
  if (t < NEXP) lcnt[t] = 0;
  float l[8]; load_logits(logits, b2, row, l);
  int i0, i1; float l0, l1;
  top2(l, i0, l0, i1, l1);
  __syncthreads();
  atomicAdd(&lcnt[i0], 1);
  atomicAdd(&lcnt[i1], 1);
  __syncthreads();
  if (t < NEXP) atomicAdd(&cnts[t], lcnt[t]);
}

__global__ void scan_kernel(const int* __restrict__ cnts, int* __restrict__ offs)
{
  if (threadIdx.x == 0) {
    int s = 0;
#pragma unroll
    for (int e = 0; e < NEXP; ++e) { offs[e] = s; s += cnts[e]; }
    offs[NEXP] = s;
  }
}

__global__ __launch_bounds__(256)
void pass_scatter(const float* __restrict__ logits, const float* __restrict__ b2,
                  const int* __restrict__ offs, int* __restrict__ cnts2,
                  int* __restrict__ rowsC, float* __restrict__ gateC)
{
  __shared__ int lcnt[NEXP];
  __shared__ int sbase[NEXP];
  const int t = threadIdx.x;
  const int row = blockIdx.x * 256 + t;
  if (t < NEXP) lcnt[t] = 0;
  float l[8]; load_logits(logits, b2, row, l);
  int i0, i1; float l0, l1;
  top2(l, i0, l0, i1, l1);
  float tt = expf(l1 - l0);            // <= 1
  float g0 = 1.f / (1.f + tt);
  float g1 = tt / (1.f + tt);
  __syncthreads();
  int r0 = atomicAdd(&lcnt[i0], 1);
  int r1 = atomicAdd(&lcnt[i1], 1);
  __syncthreads();
  if (t < NEXP) sbase[t] = atomicAdd(&cnts2[t], lcnt[t]);
  __syncthreads();
  int p0 = offs[i0] + sbase[i0] + r0;
  int p1 = offs[i1] + sbase[i1] + r1;
  rowsC[p0] = row; gateC[p0] = g0;
  rowsC[p1] = row; gateC[p1] = g1;
}

// ---------------- GEMM: C[M,N] = A[M,K] * Bt[N,K]^T (bf16 MFMA) -------------
// SPLIT: 3-term hi/lo compensated product.
// EPI 1: Cbf[crow,n] = bf16(relu(acc+bias))
// EPI 2: atomicAdd(Cf32[rows[m], n], gates[m]*(acc+bias_if_z0))
// EPI 3: v=relu(acc+bias); atomicAdd(logits[lrow][e], sum_n v*w2[n][e])
// GATHER: A row index via rows[] list.
// FUSED: expert = blockIdx.z; B/bias strided per expert; H rows offset by offs[e].
template<bool SPLIT, int EPI, bool GATHER, bool FUSED>
__global__ __launch_bounds__(256, 2)
void gemm_bt(const u16* __restrict__ A0, const u16* __restrict__ A1,
             const u16* __restrict__ B0, const u16* __restrict__ B1,
             int lda, int ldb, int K, int M,
             size_t bStrideE, int biasStrideE,
             const int* __restrict__ counts, int expertArg,
             const int* __restrict__ offs,
             const int* __restrict__ rowsC, const float* __restrict__ gatesC,
             const float* __restrict__ bias,
             const float* __restrict__ w2, float* __restrict__ logits,
             u16* __restrict__ Cbf, float* __restrict__ Cf32, int ldc)
{
  const int expert = FUSED ? (int)blockIdx.z : expertArg;
  const int Mq = counts ? counts[expert] : M;
  const int m0 = blockIdx.y * 128;
  if (m0 >= Mq) return;
  const int n0 = blockIdx.x * 128;
  const int off = offs ? offs[expert] : 0;
  const int* rows = rowsC ? rowsC + off : nullptr;
  const float* gates = gatesC ? gatesC + off : nullptr;
  const u16* B = B0 + (FUSED ? (size_t)expert * bStrideE : 0);
  const u16* Bl = SPLIT ? B1 : nullptr;
  const float* bi = bias + (FUSED ? (size_t)expert * biasStrideE : 0);
  const int z = FUSED ? 0 : (int)blockIdx.z;
  const int zOff = z * K;

  __shared__ u16 As0[128 * 32], Bs0[128 * 32];
  __shared__ u16 As1[SPLIT ? 128 * 32 : 8], Bs1[SPLIT ? 128 * 32 : 8];

  const int t = threadIdx.x;
  size_t aoff[2]; int acodd[2]; size_t boff[2];
#pragma unroll
  for (int i = 0; i < 2; ++i) {
    int gdx = i * 256 + t;
    int ar = gdx >> 2, ac = (gdx & 3) * 8;
    int am = m0 + ar;
    int amc = am < Mq ? am : (Mq - 1);
    int agr = GATHER ? rows[amc] : amc;
    if (FUSED && EPI == 2) agr += off;       // A = compact H buffer
    aoff[i] = (size_t)agr * lda + ac + zOff;
    boff[i] = (size_t)(n0 + ar) * ldb + ac + zOff;
    acodd[i] = gdx * 8;
  }

  f32x4 acc[4][4];
#pragma unroll
  for (int i = 0; i < 4; ++i)
#pragma unroll
    for (int j = 0; j < 4; ++j) acc[i][j] = (f32x4){0.f, 0.f, 0.f, 0.f};

  const int lane = t & 63, wv = t >> 6;
  const int wm = (wv >> 1) * 64, wn = (wv & 1) * 64;
  const int fr = lane & 15, fq = lane >> 4;

  for (int k0 = 0; k0 < K; k0 += 32) {
    __syncthreads();
#pragma unroll
    for (int i = 0; i < 2; ++i) {
      async16(A0 + aoff[i] + k0, &As0[acodd[i]]);
      async16(B + boff[i] + k0, &Bs0[acodd[i]]);
      if (SPLIT) {
        async16(A1 + aoff[i] + k0, &As1[acodd[i]]);
        async16(Bl + boff[i] + k0, &Bs1[acodd[i]]);
      }
    }
    __syncthreads();
    bf16x8 af[4], bfr[4], af1[4], bf1[4];
#pragma unroll
    for (int xi = 0; xi < 4; ++xi) {
      af[xi]  = *(const bf16x8*)&As0[(wm + xi * 16 + fr) * 32 + fq * 8];
      bfr[xi] = *(const bf16x8*)&Bs0[(wn + xi * 16 + fr) * 32 + fq * 8];
      if (SPLIT) {
        af1[xi] = *(const bf16x8*)&As1[(wm + xi * 16 + fr) * 32 + fq * 8];
        bf1[xi] = *(const bf16x8*)&Bs1[(wn + xi * 16 + fr) * 32 + fq * 8];
      }
    }
#pragma unroll
    for (int mt = 0; mt < 4; ++mt)
#pragma unroll
      for (int nt = 0; nt < 4; ++nt) {
        acc[mt][nt] = __builtin_amdgcn_mfma_f32_16x16x32_bf16(af[mt], bfr[nt], acc[mt][nt], 0, 0, 0);
        if (SPLIT) {
          acc[mt][nt] = __builtin_amdgcn_mfma_f32_16x16x32_bf16(af[mt], bf1[nt], acc[mt][nt], 0, 0, 0);
          acc[mt][nt] = __builtin_amdgcn_mfma_f32_16x16x32_bf16(af1[mt], bfr[nt], acc[mt][nt], 0, 0, 0);
        }
      }
  }

  // C/D layout: col = lane&15 (fr), row = fq*4 + reg
  if constexpr (EPI == 3) {
    float w2v[4][8]; float b1v[4];
#pragma unroll
    for (int nt = 0; nt < 4; ++nt) {
      const int n = n0 + wn + nt * 16 + fr;
      b1v[nt] = bi[n];
      const float4* wp = (const float4*)(w2 + (size_t)n * 8);
      float4 wa = wp[0], wb = wp[1];
      w2v[nt][0] = wa.x; w2v[nt][1] = wa.y; w2v[nt][2] = wa.z; w2v[nt][3] = wa.w;
      w2v[nt][4] = wb.x; w2v[nt][5] = wb.y; w2v[nt][6] = wb.z; w2v[nt][7] = wb.w;
    }
#pragma unroll
    for (int mt = 0; mt < 4; ++mt) {
      float pe[4][8];
#pragma unroll
      for (int r = 0; r < 4; ++r)
#pragma unroll
        for (int e = 0; e < 8; ++e) pe[r][e] = 0.f;
#pragma unroll
      for (int nt = 0; nt < 4; ++nt)
#pragma unroll
        for (int r = 0; r < 4; ++r) {
          float v = fmaxf(acc[mt][nt][r] + b1v[nt], 0.f);
#pragma unroll
          for (int e = 0; e < 8; ++e) pe[r][e] += v * w2v[nt][e];
        }
#pragma unroll
      for (int offx = 1; offx < 16; offx <<= 1)
#pragma unroll
        for (int r = 0; r < 4; ++r)
#pragma unroll
          for (int e = 0; e < 8; ++e)
            pe[r][e] += __shfl_xor(pe[r][e], offx, 64);
      if (fr == 0) {
#pragma unroll
        for (int r = 0; r < 4; ++r) {
          const int m = m0 + wm + mt * 16 + fq * 4 + r;
          if (m < Mq) {
            const int lrow = GATHER ? rows[m] : m;
#pragma unroll
            for (int e = 0; e < 8; ++e)
              atomicAdd(&logits[(size_t)lrow * 8 + e], pe[r][e]);
          }
        }
      }
    }
    return;
  }

#pragma unroll
  for (int mt = 0; mt < 4; ++mt) {
#pragma unroll
    for (int nt = 0; nt < 4; ++nt) {
      const int n = n0 + wn + nt * 16 + fr;
      const float bv = (z == 0) ? bi[n] : 0.f;
#pragma unroll
      for (int r = 0; r < 4; ++r) {
        const int m = m0 + wm + mt * 16 + fq * 4 + r;
        if (m < Mq) {
          float v = acc[mt][nt][r] + bv;
          if constexpr (EPI == 1) {
            const int crow = m + (FUSED ? off : 0);
            Cbf[(size_t)crow * ldc + n] = f2bf(fmaxf(v, 0.f));
          } else {
            atomicAdd(&Cf32[(size_t)rows[m] * ldc + n], gates[m] * v);
          }
        }
      }
    }
  }
}

extern "C" void kernel_launch(void* const* d_in, const int* in_sizes, int n_in,
                              void* d_out, int out_size, void* d_ws, size_t ws_size,
                              hipStream_t stream)
{
  const float* x    = (const float*)d_in[0];
  const float* ln_g = (const float*)d_in[1];
  const float* ln_b = (const float*)d_in[2];
  const float* r_w1 = (const float*)d_in[3];
  const float* r_b1 = (const float*)d_in[4];
  const float* r_w2 = (const float*)d_in[5];
  const float* r_b2 = (const float*)d_in[6];
  const float* e_w1 = (const float*)d_in[7];
  const float* e_b1 = (const float*)d_in[8];
  const float* e_w2 = (const float*)d_in[9];
  const float* e_b2 = (const float*)d_in[10];
  float* out = (float*)d_out;

  char* ws = (char*)d_ws;
  const size_t MB = 1024ull * 1024ull;
  u16*   xnhi = (u16*)(ws);                 // 32 MB  [N, D] bf16
  u16*   xnlo = (u16*)(ws + 32 * MB);       // 32 MB
  u16*   rw1h = (u16*)(ws + 64 * MB);       // 4 MB   [HR, D] bf16
  u16*   rw1l = (u16*)(ws + 68 * MB);       // 4 MB
  u16*   ew1t = (u16*)(ws + 72 * MB);       // 64 MB  [E][H, D] bf16
  u16*   ew2t = (u16*)(ws + 136 * MB);      // 64 MB  [E][D, H] bf16
  float* logits = (float*)(ws + 200 * MB);                    // 512 KB [N, 8]
  int*   rowsC  = (int*)(ws + 200 * MB + 512 * 1024);         // 128 KB [2N]
  float* gateC  = (float*)(ws + 200 * MB + 640 * 1024);       // 128 KB [2N]
  int*   fixL   = (int*)(ws + 200 * MB + 768 * 1024);         // 64 KB  [N]
  int*   cntb   = (int*)(ws + 200 * MB + 832 * 1024);         // 256 B
  int*   cnts   = cntb;          // [8]
  int*   cnts2  = cntb + 8;      // [8]
  int*   offs   = cntb + 16;     // [9]
  int*   cntFix = cntb + 25;     // [1]
  u16*   Hbuf = (u16*)(ws + 201 * MB);      // fused: 256 MB [2N, H]; HrB aliases
  u16*   HrB  = Hbuf;                       // 64 MB [N, HR] bf16 (router hidden)
  (void)in_sizes; (void)n_in; (void)out_size;

  const bool fused = ws_size >= 458ull * MB;

  hipMemsetAsync(cntb, 0, 256, stream);

  dim3 tb(32, 8);
  transpose_cvt<true ><<<dim3(HR / 32, DIM / 32, 1), tb, 0, stream>>>(r_w1, rw1h, rw1l, DIM, HR);
  transpose_cvt<false><<<dim3(HID / 32, DIM / 32, NEXP), tb, 0, stream>>>(e_w1, ew1t, nullptr, DIM, HID);
  transpose_cvt<false><<<dim3(DIM / 32, HID / 32, NEXP), tb, 0, stream>>>(e_w2, ew2t, nullptr, HID, DIM);

  ln_kernel<<<N_TOK, 256, 0, stream>>>(x, ln_g, ln_b, xnhi, xnlo, out);

  // router: HrB = bf16(relu(xn @ r_w1 + b1))
  gemm_bt<false, 1, false, false><<<dim3(HR / 128, N_TOK / 128), 256, 0, stream>>>(
      xnhi, nullptr, rw1h, nullptr, DIM, DIM, DIM, N_TOK, 0, 0,
      nullptr, 0, nullptr, nullptr, nullptr, r_b1, nullptr, nullptr,
      HrB, nullptr, HR);

  logits_kernel<<<N_TOK, 256, 0, stream>>>(HrB, r_w2, logits);

  pass_flag<<<N_TOK / 256, 256, 0, stream>>>(logits, r_b2, fixL, cntFix);

  // exact recompute (split 3-term) of flagged rows' logits
  gemm_bt<true, 3, true, false><<<dim3(HR / 128, N_TOK / 128), 256, 0, stream>>>(
      xnhi, xnlo, rw1h, rw1l, DIM, DIM, DIM, N_TOK, 0, 0,
      cntFix, 0, nullptr, fixL, nullptr, r_b1, r_w2, logits,
      nullptr, nullptr, 0);

  pass_count<<<N_TOK / 256, 256, 0, stream>>>(logits, r_b2, cnts);
  scan_kernel<<<1, 64, 0, stream>>>(cnts, offs);
  pass_scatter<<<N_TOK / 256, 256, 0, stream>>>(logits, r_b2, offs, cnts2, rowsC, gateC);

  if (fused) {
    // all experts in one launch each; compact H buffer [2N, HID]
    gemm_bt<false, 1, true, true><<<dim3(HID / 128, N_TOK / 128, NEXP), 256, 0, stream>>>(
        xnhi, nullptr, ew1t, nullptr, DIM, DIM, DIM, N_TOK,
        (size_t)HID * DIM, HID,
        cnts, 0, offs, rowsC, nullptr, e_b1, nullptr, nullptr,
        Hbuf, nullptr, HID);
    gemm_bt<false, 2, false, true><<<dim3(DIM / 128, N_TOK / 128, NEXP), 256, 0, stream>>>(
        Hbuf, nullptr, ew2t, nullptr, HID, HID, HID, N_TOK,
        (size_t)DIM * HID, DIM,
        cnts, 0, offs, rowsC, gateC, e_b2, nullptr, nullptr,
        nullptr, out, DIM);
  } else {
    for (int e = 0; e < NEXP; ++e) {
      gemm_bt<false, 1, true, false><<<dim3(HID / 128, N_TOK / 128), 256, 0, stream>>>(
          xnhi, nullptr, ew1t + (size_t)e * HID * DIM, nullptr,
          DIM, DIM, DIM, N_TOK, 0, 0,
          cnts, e, offs, rowsC, nullptr, e_b1 + (size_t)e * HID, nullptr, nullptr,
          Hbuf, nullptr, HID);
      gemm_bt<false, 2, false, false><<<dim3(DIM / 128, N_TOK / 128, 2), 256, 0, stream>>>(
          Hbuf, nullptr, ew2t + (size_t)e * DIM * HID, nullptr,
          HID, HID, HID / 2, N_TOK, 0, 0,
          cnts, e, offs, rowsC, gateC, e_b2 + (size_t)e * DIM, nullptr, nullptr,
          nullptr, out, DIM);
    }
  }
}